// Round 1
// baseline (1147.964 us; speedup 1.0000x reference)
//
#include <hip/hip_runtime.h>
#include <hip/hip_bf16.h>
#include <stdint.h>

#define NROWS 131072
#define KCODES 1024
#define DDIM 256
#define BM 128
#define BN 128
#define BK 32

typedef __attribute__((ext_vector_type(4))) float f32x4;
typedef __attribute__((ext_vector_type(8))) short s16x8;
typedef __attribute__((ext_vector_type(4))) short s16x4;

__device__ __forceinline__ unsigned short f2bf(float f) {
  unsigned int u = __float_as_uint(f);
  u += 0x7FFFu + ((u >> 16) & 1u);   // round-to-nearest-even
  return (unsigned short)(u >> 16);
}
__device__ __forceinline__ float bf2f(unsigned short h) {
  return __uint_as_float(((unsigned int)h) << 16);
}
__device__ __forceinline__ float wred(float v) {
#pragma unroll
  for (int s = 1; s < 64; s <<= 1) v += __shfl_xor(v, s, 64);
  return v;
}

// ---------------- prep: normalize W, split hi/lo, en_sq ----------------
__global__ __launch_bounds__(256) void prep_w(const float* __restrict__ W,
    float* __restrict__ en, unsigned short* __restrict__ enh,
    unsigned short* __restrict__ enl, float* __restrict__ ensq) {
  int wid = threadIdx.x >> 6, lane = threadIdx.x & 63;
  int k = blockIdx.x * 4 + wid;
  float4 w4 = ((const float4*)(W + (size_t)k * DDIM))[lane];
  float ss = wred(w4.x * w4.x + w4.y * w4.y + w4.z * w4.z + w4.w * w4.w);
  float mx = fmaxf(sqrtf(ss), 1e-12f);
  float4 e4;
  e4.x = w4.x / mx; e4.y = w4.y / mx; e4.z = w4.z / mx; e4.w = w4.w / mx;
  ((float4*)(en + (size_t)k * DDIM))[lane] = e4;
  unsigned short h0 = f2bf(e4.x), h1 = f2bf(e4.y), h2 = f2bf(e4.z), h3 = f2bf(e4.w);
  s16x4 hv = { (short)h0, (short)h1, (short)h2, (short)h3 };
  s16x4 lv = { (short)f2bf(e4.x - bf2f(h0)), (short)f2bf(e4.y - bf2f(h1)),
               (short)f2bf(e4.z - bf2f(h2)), (short)f2bf(e4.w - bf2f(h3)) };
  ((s16x4*)(enh + (size_t)k * DDIM))[lane] = hv;
  ((s16x4*)(enl + (size_t)k * DDIM))[lane] = lv;
  float sq = wred(e4.x * e4.x + e4.y * e4.y + e4.z * e4.z + e4.w * e4.w);
  if (lane == 0) ensq[k] = sq;
}

// ---------------- prep: normalize f rows, split hi/lo ----------------
__global__ __launch_bounds__(256) void prep_f(const float* __restrict__ f,
    unsigned short* __restrict__ fnh, unsigned short* __restrict__ fnl) {
  int wid = threadIdx.x >> 6, lane = threadIdx.x & 63;
  int n = blockIdx.x * 4 + wid;
  float4 v = ((const float4*)(f + (size_t)n * DDIM))[lane];
  float ss = wred(v.x * v.x + v.y * v.y + v.z * v.z + v.w * v.w);
  float mx = fmaxf(sqrtf(ss), 1e-12f);
  float4 e4;
  e4.x = v.x / mx; e4.y = v.y / mx; e4.z = v.z / mx; e4.w = v.w / mx;
  unsigned short h0 = f2bf(e4.x), h1 = f2bf(e4.y), h2 = f2bf(e4.z), h3 = f2bf(e4.w);
  s16x4 hv = { (short)h0, (short)h1, (short)h2, (short)h3 };
  s16x4 lv = { (short)f2bf(e4.x - bf2f(h0)), (short)f2bf(e4.y - bf2f(h1)),
               (short)f2bf(e4.z - bf2f(h2)), (short)f2bf(e4.w - bf2f(h3)) };
  ((s16x4*)(fnh + (size_t)n * DDIM))[lane] = hv;
  ((s16x4*)(fnl + (size_t)n * DDIM))[lane] = lv;
}

// ---------------- GEMM (3-term bf16 split) + fused per-block argmin ----------------
// Grid 8192 = 1024 row-tiles x 8 code-tiles. XCD swizzle: each XCD sweeps ct inner.
// LDS XOR swizzle: byte bits[5:4] ^= row bits[1:0]  (involution; applied to stage
// source offset AND fragment read offset; LDS dest stays linear per m104/m173).
__global__ __launch_bounds__(256, 2) void gemm3(
    const unsigned short* __restrict__ fnh, const unsigned short* __restrict__ fnl,
    const unsigned short* __restrict__ enh, const unsigned short* __restrict__ enl,
    const float* __restrict__ ensq, float2* __restrict__ partials) {
  __shared__ unsigned short lds[2][4][BM * BK];   // 64 KB: [buf][Ah,Al,Bh,Bl]
  int t = threadIdx.x;
  int bid = blockIdx.x;
  int x = bid & 7, jj = bid >> 3;
  int rt = x * 128 + (jj >> 3);
  int ct = jj & 7;
  int bm0 = rt * BM, bc0 = ct * BN;
  int lane = t & 63, wid = t >> 6;
  int wr = wid >> 1, wc = wid & 1;
  int l15 = lane & 15, h4 = lane >> 4;

  f32x4 acc[4][4] = {};

  const unsigned short* bases[4] = { fnh, fnl, enh, enl };

  auto stage = [&](int buf, int kt) {
#pragma unroll
    for (int q = 0; q < 4; ++q) {
      const unsigned short* bp = bases[q];
      int rbase = (q < 2) ? bm0 : bc0;
#pragma unroll
      for (int i = 0; i < 2; ++i) {
        int ci = i * 256 + t;                    // 16B chunk id, 0..511
        int row = ci >> 2;                       // 4 chunks per 32-elem row
        int kc = (((ci & 3) ^ (row & 3)) << 3);  // swizzled source k-offset (elems)
        const void* src = bp + (size_t)(rbase + row) * DDIM + kt * BK + kc;
        void* dst = (void*)&lds[buf][q][(i * 256 + wid * 64) * 8];
        __builtin_amdgcn_global_load_lds(
            (const __attribute__((address_space(1))) unsigned int*)src,
            (__attribute__((address_space(3))) unsigned int*)dst, 16, 0, 0);
      }
    }
  };

  stage(0, 0);
  for (int kt = 0; kt < 8; ++kt) {
    __syncthreads();                 // implicit vmcnt(0) drain -> tile kt ready
    if (kt < 7) stage((kt + 1) & 1, kt + 1);
    int buf = kt & 1;
    s16x8 ah[4], al[4], bh[4], bl[4];
#pragma unroll
    for (int m = 0; m < 4; ++m) {
      int row = wr * 64 + m * 16 + l15;
      int ro = row * BK + ((h4 ^ (row & 3)) << 3);
      ah[m] = *(const s16x8*)&lds[buf][0][ro];
      al[m] = *(const s16x8*)&lds[buf][1][ro];
    }
#pragma unroll
    for (int n = 0; n < 4; ++n) {
      int row = wc * 64 + n * 16 + l15;
      int ro = row * BK + ((h4 ^ (row & 3)) << 3);
      bh[n] = *(const s16x8*)&lds[buf][2][ro];
      bl[n] = *(const s16x8*)&lds[buf][3][ro];
    }
#pragma unroll
    for (int m = 0; m < 4; ++m)
#pragma unroll
      for (int n = 0; n < 4; ++n) {
        acc[m][n] = __builtin_amdgcn_mfma_f32_16x16x32_bf16(ah[m], bh[n], acc[m][n], 0, 0, 0);
        acc[m][n] = __builtin_amdgcn_mfma_f32_16x16x32_bf16(ah[m], bl[n], acc[m][n], 0, 0, 0);
        acc[m][n] = __builtin_amdgcn_mfma_f32_16x16x32_bf16(al[m], bh[n], acc[m][n], 0, 0, 0);
      }
  }

  // epilogue: dist = en_sq[c] - 2*dot ; per-row argmin (first-index tiebreak)
  float esq[4];
#pragma unroll
  for (int n = 0; n < 4; ++n) esq[n] = ensq[bc0 + wc * 64 + n * 16 + l15];

  float2* red = (float2*)lds;   // overlay buf0 (no longer read)
#pragma unroll
  for (int m = 0; m < 4; ++m) {
#pragma unroll
    for (int j = 0; j < 4; ++j) {
      float bd = fmaf(-2.f, acc[m][0][j], esq[0]);
      int bc_ = bc0 + wc * 64 + l15;
#pragma unroll
      for (int n = 1; n < 4; ++n) {
        float d = fmaf(-2.f, acc[m][n][j], esq[n]);
        int c = bc0 + wc * 64 + n * 16 + l15;
        if (d < bd) { bd = d; bc_ = c; }
      }
#pragma unroll
      for (int s = 1; s < 16; s <<= 1) {
        float od = __shfl_xor(bd, s, 64);
        int oc = __shfl_xor(bc_, s, 64);
        if (od < bd || (od == bd && oc < bc_)) { bd = od; bc_ = oc; }
      }
      if (l15 == 0)
        red[wc * BM + wr * 64 + m * 16 + h4 * 4 + j] = make_float2(bd, __int_as_float(bc_));
    }
  }
  __syncthreads();
  if (t < BM) {
    float2 p0 = red[t];
    float2 p1 = red[BM + t];
    float d = p0.x; int c = __float_as_int(p0.y);
    int c1 = __float_as_int(p1.y);
    if (p1.x < d || (p1.x == d && c1 < c)) { d = p1.x; c = c1; }
    partials[(size_t)(bm0 + t) * 8 + ct] = make_float2(d, __int_as_float(c));
  }
}

// ---------------- reduce 8 partials per row -> final idx ----------------
__global__ __launch_bounds__(256) void reduce_k(const float2* __restrict__ partials,
                                                int* __restrict__ idx) {
  int r = blockIdx.x * 256 + threadIdx.x;
  const float2* p = partials + (size_t)r * 8;
  float d = p[0].x; int c = __float_as_int(p[0].y);
#pragma unroll
  for (int i = 1; i < 8; ++i) {
    float2 q = p[i];
    int qc = __float_as_int(q.y);
    if (q.x < d || (q.x == d && qc < c)) { d = q.x; c = qc; }
  }
  idx[r] = c;
}

// ---------------- fused outputs: quantized, one-hot, loss, histogram ----------------
__global__ __launch_bounds__(256) void outputs_k(const float* __restrict__ f,
    const int* __restrict__ idx, const float* __restrict__ en,
    float* __restrict__ outq, float* __restrict__ enc,
    int* __restrict__ hist, double* __restrict__ lacc) {
  int wid = threadIdx.x >> 6, lane = threadIdx.x & 63;
  int n = blockIdx.x * 4 + wid;
  int id = idx[n];
  float4 fv = ((const float4*)(f + (size_t)n * DDIM))[lane];
  float ss = wred(fv.x * fv.x + fv.y * fv.y + fv.z * fv.z + fv.w * fv.w);
  float mx = fmaxf(sqrtf(ss), 1e-12f);
  float4 ev = ((const float4*)(en + (size_t)id * DDIM))[lane];
  ((float4*)(outq + (size_t)n * DDIM))[lane] = ev;   // quantized_st == en[idx]
  float dx = ev.x - fv.x / mx;
  float dy = ev.y - fv.y / mx;
  float dz = ev.z - fv.z / mx;
  float dw = ev.w - fv.w / mx;
  float ls = wred(dx * dx + dy * dy + dz * dz + dw * dw);
  if (lane == 0) {
    atomicAdd(&lacc[blockIdx.x & 255], (double)ls);
    atomicAdd(&hist[id], 1);
  }
  // one-hot row: base only 8B-aligned -> float2 stores
  float* rowp = enc + (size_t)n * KCODES + lane * 16;
#pragma unroll
  for (int i = 0; i < 8; ++i) {
    int c0 = lane * 16 + i * 2;
    ((float2*)rowp)[i] = make_float2(c0 == id ? 1.f : 0.f, (c0 + 1) == id ? 1.f : 0.f);
  }
}

// ---------------- finalize scalars ----------------
__global__ __launch_bounds__(256) void finalize_k(const int* __restrict__ hist,
    const double* __restrict__ lacc, float* __restrict__ out) {
  __shared__ double sd[256];
  __shared__ double se[256];
  int t = threadIdx.x;
  double e = 0.0;
#pragma unroll
  for (int i = 0; i < 4; ++i) {
    int c = hist[t * 4 + i];
    float p = (float)c * (1.0f / 131072.0f);
    e += (double)(p * logf(p + 1e-10f));
  }
  sd[t] = lacc[t];
  se[t] = e;
  __syncthreads();
  for (int s = 128; s > 0; s >>= 1) {
    if (t < s) { sd[t] += sd[t + s]; se[t] += se[t + s]; }
    __syncthreads();
  }
  if (t == 0) {
    out[33554432] = (float)(1.25 * (sd[0] / ((double)NROWS * (double)DDIM)));
    out[33554433] = expf(-(float)se[0]);
  }
}

extern "C" void kernel_launch(void* const* d_in, const int* in_sizes, int n_in,
                              void* d_out, int out_size, void* d_ws, size_t ws_size,
                              hipStream_t stream) {
  const float* f = (const float*)d_in[0];
  const float* W = (const float*)d_in[1];
  float* out = (float*)d_out;
  char* ws = (char*)d_ws;

  // ws layout (~2.6 MB)
  int*    hist = (int*)ws;                                   // 4 KB (memset)
  double* lacc = (double*)(ws + 4096);                       // 2 KB (memset)
  float*  ensq = (float*)(ws + 8192);                        // 4 KB
  float*  en   = (float*)(ws + 12288);                       // 1 MB
  unsigned short* enh = (unsigned short*)(ws + 12288 + 1048576);           // 512 KB
  unsigned short* enl = (unsigned short*)(ws + 12288 + 1048576 + 524288);  // 512 KB
  int*    idx  = (int*)(ws + 12288 + 2097152);               // 512 KB

  // big scratch inside d_out's encodings region (fully overwritten by outputs_k)
  char* ob = (char*)d_out;
  const size_t S = 134217984;   // 256-aligned, past quantized+scalars
  unsigned short* fnh = (unsigned short*)(ob + S);                 // 64 MB
  unsigned short* fnl = (unsigned short*)(ob + S + 67108864);      // 64 MB
  float2* partials = (float2*)(ob + S + 134217728);                // 8 MB
  float* enc = out + 33554434;

  hipMemsetAsync(ws, 0, 8192, stream);
  prep_w<<<KCODES / 4, 256, 0, stream>>>(W, en, enh, enl, ensq);
  prep_f<<<NROWS / 4, 256, 0, stream>>>(f, fnh, fnl);
  gemm3<<<(NROWS / BM) * (KCODES / BN), 256, 0, stream>>>(fnh, fnl, enh, enl, ensq, partials);
  reduce_k<<<NROWS / 256, 256, 0, stream>>>(partials, idx);
  outputs_k<<<NROWS / 4, 256, 0, stream>>>(f, idx, en, out, enc, hist, lacc);
  finalize_k<<<1, 256, 0, stream>>>(hist, lacc, out);
}

// Round 4
// 1042.111 us; speedup vs baseline: 1.1016x; 1.1016x over previous
//
#include <hip/hip_runtime.h>
#include <hip/hip_bf16.h>
#include <stdint.h>

#define NROWS 131072
#define KCODES 1024
#define DDIM 256
#define BM 128
#define BK 32

typedef __attribute__((ext_vector_type(4))) float f32x4;
typedef __attribute__((ext_vector_type(8))) short s16x8;
typedef __attribute__((ext_vector_type(4))) short s16x4;

__device__ __forceinline__ unsigned short f2bf(float f) {
  unsigned int u = __float_as_uint(f);
  u += 0x7FFFu + ((u >> 16) & 1u);   // round-to-nearest-even
  return (unsigned short)(u >> 16);
}
__device__ __forceinline__ float bf2f(unsigned short h) {
  return __uint_as_float(((unsigned int)h) << 16);
}
__device__ __forceinline__ float wred(float v) {
#pragma unroll
  for (int s = 1; s < 64; s <<= 1) v += __shfl_xor(v, s, 64);
  return v;
}

// ---------------- prep: normalize W, split hi/lo, en_sq ----------------
__global__ __launch_bounds__(256) void prep_w(const float* __restrict__ W,
    float* __restrict__ en, unsigned short* __restrict__ enh,
    unsigned short* __restrict__ enl, float* __restrict__ ensq) {
  int wid = threadIdx.x >> 6, lane = threadIdx.x & 63;
  int k = blockIdx.x * 4 + wid;
  float4 w4 = ((const float4*)(W + (size_t)k * DDIM))[lane];
  float ss = wred(w4.x * w4.x + w4.y * w4.y + w4.z * w4.z + w4.w * w4.w);
  float mx = fmaxf(sqrtf(ss), 1e-12f);
  float4 e4;
  e4.x = w4.x / mx; e4.y = w4.y / mx; e4.z = w4.z / mx; e4.w = w4.w / mx;
  ((float4*)(en + (size_t)k * DDIM))[lane] = e4;
  unsigned short h0 = f2bf(e4.x), h1 = f2bf(e4.y), h2 = f2bf(e4.z), h3 = f2bf(e4.w);
  s16x4 hv = { (short)h0, (short)h1, (short)h2, (short)h3 };
  s16x4 lv = { (short)f2bf(e4.x - bf2f(h0)), (short)f2bf(e4.y - bf2f(h1)),
               (short)f2bf(e4.z - bf2f(h2)), (short)f2bf(e4.w - bf2f(h3)) };
  ((s16x4*)(enh + (size_t)k * DDIM))[lane] = hv;
  ((s16x4*)(enl + (size_t)k * DDIM))[lane] = lv;
  float sq = wred(e4.x * e4.x + e4.y * e4.y + e4.z * e4.z + e4.w * e4.w);
  if (lane == 0) ensq[k] = sq;
}

// ---------------- prep: normalize f rows, split hi/lo ----------------
__global__ __launch_bounds__(256) void prep_f(const float* __restrict__ f,
    unsigned short* __restrict__ fnh, unsigned short* __restrict__ fnl) {
  int wid = threadIdx.x >> 6, lane = threadIdx.x & 63;
  int n = blockIdx.x * 4 + wid;
  float4 v = ((const float4*)(f + (size_t)n * DDIM))[lane];
  float ss = wred(v.x * v.x + v.y * v.y + v.z * v.z + v.w * v.w);
  float mx = fmaxf(sqrtf(ss), 1e-12f);
  float4 e4;
  e4.x = v.x / mx; e4.y = v.y / mx; e4.z = v.z / mx; e4.w = v.w / mx;
  unsigned short h0 = f2bf(e4.x), h1 = f2bf(e4.y), h2 = f2bf(e4.z), h3 = f2bf(e4.w);
  s16x4 hv = { (short)h0, (short)h1, (short)h2, (short)h3 };
  s16x4 lv = { (short)f2bf(e4.x - bf2f(h0)), (short)f2bf(e4.y - bf2f(h1)),
               (short)f2bf(e4.z - bf2f(h2)), (short)f2bf(e4.w - bf2f(h3)) };
  ((s16x4*)(fnh + (size_t)n * DDIM))[lane] = hv;
  ((s16x4*)(fnl + (size_t)n * DDIM))[lane] = lv;
}

// ---------------- GEMM (3-term bf16 split) + full-row argmin ----------------
// 1024 blocks, each owns 128 rows x all 1024 codes. 64 flat iterations
// it = ct*8 + kt, double-buffered global_load_lds staging (m97 structure).
// LDS XOR swizzle uses (row>>2)&3 (2-way residual conflict = free, m136),
// applied to BOTH stage source k-offset and fragment read (involution, rule #21).
__global__ __launch_bounds__(256, 2) void gemm3(
    const unsigned short* __restrict__ fnh, const unsigned short* __restrict__ fnl,
    const unsigned short* __restrict__ enh, const unsigned short* __restrict__ enl,
    const float* __restrict__ ensq, int* __restrict__ idx) {
  __shared__ unsigned short lds[2][4][BM * BK];   // 64 KB: [buf][Ah,Al,Bh,Bl]
  int t = threadIdx.x;
  int bm0 = blockIdx.x * BM;
  int lane = t & 63, wid = t >> 6;
  int wr = wid >> 1, wc = wid & 1;
  int l15 = lane & 15, h4 = lane >> 4;

  float run_d[4][4];
  int run_c[4][4];
#pragma unroll
  for (int m = 0; m < 4; ++m)
#pragma unroll
    for (int j = 0; j < 4; ++j) { run_d[m][j] = 1e30f; run_c[m][j] = 0; }

  auto stage = [&](int buf, int it) {
    int ct = it >> 3, kt = it & 7;
#pragma unroll
    for (int i = 0; i < 2; ++i) {
      int ci = i * 256 + t;                        // 16B chunk id, 0..511
      int row = ci >> 2;                           // 4 chunks per 32-elem row
      int kc = (((ci & 3) ^ ((row >> 2) & 3)) << 3);  // swizzled source k-off (elems)
      int koff = kt * BK + kc;
      unsigned int dstb = (unsigned int)((i * 256 + wid * 64) * 8);
      const unsigned short* sAh = fnh + (size_t)(bm0 + row) * DDIM + koff;
      const unsigned short* sAl = fnl + (size_t)(bm0 + row) * DDIM + koff;
      const unsigned short* sBh = enh + (size_t)(ct * 128 + row) * DDIM + koff;
      const unsigned short* sBl = enl + (size_t)(ct * 128 + row) * DDIM + koff;
      __builtin_amdgcn_global_load_lds(
          (const __attribute__((address_space(1))) unsigned int*)sAh,
          (__attribute__((address_space(3))) unsigned int*)&lds[buf][0][dstb], 16, 0, 0);
      __builtin_amdgcn_global_load_lds(
          (const __attribute__((address_space(1))) unsigned int*)sAl,
          (__attribute__((address_space(3))) unsigned int*)&lds[buf][1][dstb], 16, 0, 0);
      __builtin_amdgcn_global_load_lds(
          (const __attribute__((address_space(1))) unsigned int*)sBh,
          (__attribute__((address_space(3))) unsigned int*)&lds[buf][2][dstb], 16, 0, 0);
      __builtin_amdgcn_global_load_lds(
          (const __attribute__((address_space(1))) unsigned int*)sBl,
          (__attribute__((address_space(3))) unsigned int*)&lds[buf][3][dstb], 16, 0, 0);
    }
  };

  f32x4 acc[4][4] = {};
  stage(0, 0);
  for (int it = 0; it < 64; ++it) {
    __syncthreads();                 // compiler drains vmcnt(0) -> tile ready
    if (it < 63) stage((it + 1) & 1, it + 1);
    int buf = it & 1;
    s16x8 ah[4], al[4], bh[4], bl[4];
#pragma unroll
    for (int m = 0; m < 4; ++m) {
      int row = wr * 64 + m * 16 + l15;
      int ro = row * BK + ((h4 ^ ((row >> 2) & 3)) << 3);
      ah[m] = *(const s16x8*)&lds[buf][0][ro];
      al[m] = *(const s16x8*)&lds[buf][1][ro];
    }
#pragma unroll
    for (int n = 0; n < 4; ++n) {
      int row = wc * 64 + n * 16 + l15;
      int ro = row * BK + ((h4 ^ ((row >> 2) & 3)) << 3);
      bh[n] = *(const s16x8*)&lds[buf][2][ro];
      bl[n] = *(const s16x8*)&lds[buf][3][ro];
    }
#pragma unroll
    for (int m = 0; m < 4; ++m)
#pragma unroll
      for (int n = 0; n < 4; ++n) {
        acc[m][n] = __builtin_amdgcn_mfma_f32_16x16x32_bf16(ah[m], bh[n], acc[m][n], 0, 0, 0);
        acc[m][n] = __builtin_amdgcn_mfma_f32_16x16x32_bf16(ah[m], bl[n], acc[m][n], 0, 0, 0);
        acc[m][n] = __builtin_amdgcn_mfma_f32_16x16x32_bf16(al[m], bh[n], acc[m][n], 0, 0, 0);
      }
    if ((it & 7) == 7) {             // end of a ct tile: fold into running argmin
      int ct = it >> 3;
#pragma unroll
      for (int n = 0; n < 4; ++n) {
        float es = ensq[ct * 128 + wc * 64 + n * 16 + l15];
        int c = ct * 128 + wc * 64 + n * 16 + l15;
#pragma unroll
        for (int m = 0; m < 4; ++m)
#pragma unroll
          for (int j = 0; j < 4; ++j) {
            float d = fmaf(-2.f, acc[m][n][j], es);
            if (d < run_d[m][j]) { run_d[m][j] = d; run_c[m][j] = c; }
            acc[m][n][j] = 0.f;
          }
      }
    }
  }

  // final: reduce across the 16 l15 lanes per (m,j) slot, then combine wc halves
  float2* red = (float2*)lds;   // overlays buf0; last iteration used buf1
#pragma unroll
  for (int m = 0; m < 4; ++m)
#pragma unroll
    for (int j = 0; j < 4; ++j) {
      float bd = run_d[m][j];
      int bc = run_c[m][j];
#pragma unroll
      for (int s = 1; s < 16; s <<= 1) {
        float od = __shfl_xor(bd, s, 64);
        int oc = __shfl_xor(bc, s, 64);
        if (od < bd || (od == bd && oc < bc)) { bd = od; bc = oc; }
      }
      if (l15 == 0)
        red[wc * BM + wr * 64 + m * 16 + h4 * 4 + j] = make_float2(bd, __int_as_float(bc));
    }
  __syncthreads();
  if (t < BM) {
    float2 p0 = red[t];
    float2 p1 = red[BM + t];
    int c0 = __float_as_int(p0.y), c1 = __float_as_int(p1.y);
    int c = (p1.x < p0.x || (p1.x == p0.x && c1 < c0)) ? c1 : c0;
    idx[bm0 + t] = c;
  }
}

// ---------------- fused outputs: quantized, loss, histogram, one-hot scatter ----------------
// (one-hot zeros come from a hipMemsetAsync fill before this kernel)
__global__ __launch_bounds__(256) void outputs_k(const float* __restrict__ f,
    const int* __restrict__ idx, const float* __restrict__ en,
    float* __restrict__ outq, float* __restrict__ enc,
    int* __restrict__ hist, double* __restrict__ lacc) {
  int wid = threadIdx.x >> 6, lane = threadIdx.x & 63;
  int n = blockIdx.x * 4 + wid;
  int id = idx[n];
  float4 fv = ((const float4*)(f + (size_t)n * DDIM))[lane];
  float ss = wred(fv.x * fv.x + fv.y * fv.y + fv.z * fv.z + fv.w * fv.w);
  float mx = fmaxf(sqrtf(ss), 1e-12f);
  float4 ev = ((const float4*)(en + (size_t)id * DDIM))[lane];
  ((float4*)(outq + (size_t)n * DDIM))[lane] = ev;   // quantized_st == en[idx]
  float dx = ev.x - fv.x / mx;
  float dy = ev.y - fv.y / mx;
  float dz = ev.z - fv.z / mx;
  float dw = ev.w - fv.w / mx;
  float ls = wred(dx * dx + dy * dy + dz * dz + dw * dw);
  if (lane == 0) {
    atomicAdd(&lacc[blockIdx.x & 255], (double)ls);
    atomicAdd(&hist[id], 1);
    enc[(size_t)n * KCODES + id] = 1.0f;             // scatter the single 1
  }
}

// ---------------- finalize scalars ----------------
__global__ __launch_bounds__(256) void finalize_k(const int* __restrict__ hist,
    const double* __restrict__ lacc, float* __restrict__ out) {
  __shared__ double sd[256];
  __shared__ double se[256];
  int t = threadIdx.x;
  double e = 0.0;
#pragma unroll
  for (int i = 0; i < 4; ++i) {
    int c = hist[t * 4 + i];
    float p = (float)c * (1.0f / 131072.0f);
    e += (double)(p * logf(p + 1e-10f));
  }
  sd[t] = lacc[t];
  se[t] = e;
  __syncthreads();
  for (int s = 128; s > 0; s >>= 1) {
    if (t < s) { sd[t] += sd[t + s]; se[t] += se[t + s]; }
    __syncthreads();
  }
  if (t == 0) {
    out[33554432] = (float)(1.25 * (sd[0] / ((double)NROWS * (double)DDIM)));
    out[33554433] = expf(-(float)se[0]);
  }
}

extern "C" void kernel_launch(void* const* d_in, const int* in_sizes, int n_in,
                              void* d_out, int out_size, void* d_ws, size_t ws_size,
                              hipStream_t stream) {
  const float* f = (const float*)d_in[0];
  const float* W = (const float*)d_in[1];
  float* out = (float*)d_out;
  char* ws = (char*)d_ws;

  // ws layout (~2.6 MB)
  int*    hist = (int*)ws;                                   // 4 KB (memset)
  double* lacc = (double*)(ws + 4096);                       // 2 KB (memset)
  float*  ensq = (float*)(ws + 8192);                        // 4 KB
  float*  en   = (float*)(ws + 12288);                       // 1 MB
  unsigned short* enh = (unsigned short*)(ws + 12288 + 1048576);           // 512 KB
  unsigned short* enl = (unsigned short*)(ws + 12288 + 1048576 + 524288);  // 512 KB
  int*    idx  = (int*)(ws + 12288 + 2097152);               // 512 KB

  // big scratch inside d_out's encodings region; gemm3 consumes it BEFORE the
  // enc-region memset + outputs_k overwrite it.
  char* ob = (char*)d_out;
  const size_t S = 134217984;   // 256-aligned, past quantized+scalars
  unsigned short* fnh = (unsigned short*)(ob + S);                 // 64 MB
  unsigned short* fnl = (unsigned short*)(ob + S + 67108864);      // 64 MB
  float* enc = out + 33554434;

  hipMemsetAsync(ws, 0, 8192, stream);
  prep_w<<<KCODES / 4, 256, 0, stream>>>(W, en, enh, enl, ensq);
  prep_f<<<NROWS / 4, 256, 0, stream>>>(f, fnh, fnl);
  gemm3<<<NROWS / BM, 256, 0, stream>>>(fnh, fnl, enh, enl, ensq, idx);
  hipMemsetAsync((void*)enc, 0, 536870912ULL, stream);   // zero one-hot region
  outputs_k<<<NROWS / 4, 256, 0, stream>>>(f, idx, en, out, enc, hist, lacc);
  finalize_k<<<1, 256, 0, stream>>>(hist, lacc, out);
}

// Round 5
// 985.534 us; speedup vs baseline: 1.1648x; 1.0574x over previous
//
#include <hip/hip_runtime.h>
#include <hip/hip_bf16.h>
#include <stdint.h>

#define NROWS 131072
#define KCODES 1024
#define DDIM 256
#define BM2 256          // rows per block (8 waves x 32 rows)
#define CT 64            // codes per LDS tile
#define NCT 16           // 1024/64

typedef __attribute__((ext_vector_type(4))) float f32x4;
typedef __attribute__((ext_vector_type(8))) short s16x8;
typedef __attribute__((ext_vector_type(4))) short s16x4;

__device__ __forceinline__ unsigned short f2bf(float f) {
  unsigned int u = __float_as_uint(f);
  u += 0x7FFFu + ((u >> 16) & 1u);   // round-to-nearest-even
  return (unsigned short)(u >> 16);
}
__device__ __forceinline__ float bf2f(unsigned short h) {
  return __uint_as_float(((unsigned int)h) << 16);
}
__device__ __forceinline__ float wred(float v) {
#pragma unroll
  for (int s = 1; s < 64; s <<= 1) v += __shfl_xor(v, s, 64);
  return v;
}

// ---------------- prep: normalize W, split hi/lo, en_sq ----------------
__global__ __launch_bounds__(256) void prep_w(const float* __restrict__ W,
    float* __restrict__ en, unsigned short* __restrict__ enh,
    unsigned short* __restrict__ enl, float* __restrict__ ensq) {
  int wid = threadIdx.x >> 6, lane = threadIdx.x & 63;
  int k = blockIdx.x * 4 + wid;
  float4 w4 = ((const float4*)(W + (size_t)k * DDIM))[lane];
  float ss = wred(w4.x * w4.x + w4.y * w4.y + w4.z * w4.z + w4.w * w4.w);
  float mx = fmaxf(sqrtf(ss), 1e-12f);
  float4 e4;
  e4.x = w4.x / mx; e4.y = w4.y / mx; e4.z = w4.z / mx; e4.w = w4.w / mx;
  ((float4*)(en + (size_t)k * DDIM))[lane] = e4;
  unsigned short h0 = f2bf(e4.x), h1 = f2bf(e4.y), h2 = f2bf(e4.z), h3 = f2bf(e4.w);
  s16x4 hv = { (short)h0, (short)h1, (short)h2, (short)h3 };
  s16x4 lv = { (short)f2bf(e4.x - bf2f(h0)), (short)f2bf(e4.y - bf2f(h1)),
               (short)f2bf(e4.z - bf2f(h2)), (short)f2bf(e4.w - bf2f(h3)) };
  ((s16x4*)(enh + (size_t)k * DDIM))[lane] = hv;
  ((s16x4*)(enl + (size_t)k * DDIM))[lane] = lv;
  float sq = wred(e4.x * e4.x + e4.y * e4.y + e4.z * e4.z + e4.w * e4.w);
  if (lane == 0) ensq[k] = sq;
}

// ---------------- prep: normalize f rows, split hi/lo ----------------
__global__ __launch_bounds__(256) void prep_f(const float* __restrict__ f,
    unsigned short* __restrict__ fnh, unsigned short* __restrict__ fnl) {
  int wid = threadIdx.x >> 6, lane = threadIdx.x & 63;
  int n = blockIdx.x * 4 + wid;
  float4 v = ((const float4*)(f + (size_t)n * DDIM))[lane];
  float ss = wred(v.x * v.x + v.y * v.y + v.z * v.z + v.w * v.w);
  float mx = fmaxf(sqrtf(ss), 1e-12f);
  float4 e4;
  e4.x = v.x / mx; e4.y = v.y / mx; e4.z = v.z / mx; e4.w = v.w / mx;
  unsigned short h0 = f2bf(e4.x), h1 = f2bf(e4.y), h2 = f2bf(e4.z), h3 = f2bf(e4.w);
  s16x4 hv = { (short)h0, (short)h1, (short)h2, (short)h3 };
  s16x4 lv = { (short)f2bf(e4.x - bf2f(h0)), (short)f2bf(e4.y - bf2f(h1)),
               (short)f2bf(e4.z - bf2f(h2)), (short)f2bf(e4.w - bf2f(h3)) };
  ((s16x4*)(fnh + (size_t)n * DDIM))[lane] = hv;
  ((s16x4*)(fnl + (size_t)n * DDIM))[lane] = lv;
}

// ---------------- A-stationary 3-term GEMM + full-row argmin ----------------
// 512 blocks x 512 threads (8 waves). Each wave owns 32 rows; its full-K A
// fragments (hi+lo) live in registers, loaded once from global (same
// lane->(row=l15, kchunk=h4) fragment mapping the round-4 LDS reads used).
// B (codebook) streams through LDS in 64-code full-K tiles, double-buffered
// (2buf x hi/lo x 32KB = 128KB). Chunk-XOR swizzle X = cc ^ (code&7)
// (involution; applied to stage SOURCE and ds_read) spreads the 512B-stride
// code rows across all banks -> minimal 8 words/bank.
__global__ __launch_bounds__(512, 2) void gemm3(
    const unsigned short* __restrict__ fnh, const unsigned short* __restrict__ fnl,
    const unsigned short* __restrict__ enh, const unsigned short* __restrict__ enl,
    const float* __restrict__ ensq, int* __restrict__ idx) {
  __shared__ unsigned short ldsB[2][2][CT * DDIM];   // 128 KB
  int t = threadIdx.x;
  int lane = t & 63, wid = t >> 6;
  int l15 = lane & 15, h4 = lane >> 4;
  int wrow = blockIdx.x * BM2 + wid * 32;

  // --- A fragments: 2 m-frags x 8 k-slices, hi+lo (128 VGPR), read once ---
  s16x8 ah[2][8], al[2][8];
#pragma unroll
  for (int m = 0; m < 2; ++m) {
    const unsigned short* rh = fnh + (size_t)(wrow + m * 16 + l15) * DDIM + h4 * 8;
    const unsigned short* rl = fnl + (size_t)(wrow + m * 16 + l15) * DDIM + h4 * 8;
#pragma unroll
    for (int ks = 0; ks < 8; ++ks) {
      ah[m][ks] = *(const s16x8*)(rh + ks * 32);
      al[m][ks] = *(const s16x8*)(rl + ks * 32);
    }
  }

  auto stageB = [&](int buf, int ct) {
#pragma unroll
    for (int i = 0; i < 4; ++i) {
      int ci = i * 512 + t;                 // 16B chunk 0..2047
      int c = ci >> 5;                      // local code row 0..63
      int cc = (ci & 31) ^ (c & 7);         // source chunk (involution)
      const unsigned short* sh = enh + (size_t)(ct * CT + c) * DDIM + cc * 8;
      const unsigned short* sl = enl + (size_t)(ct * CT + c) * DDIM + cc * 8;
      unsigned int dst = (unsigned int)((i * 512 + wid * 64) * 8);  // elems, wave-uniform
      __builtin_amdgcn_global_load_lds(
          (const __attribute__((address_space(1))) unsigned int*)sh,
          (__attribute__((address_space(3))) unsigned int*)&ldsB[buf][0][dst], 16, 0, 0);
      __builtin_amdgcn_global_load_lds(
          (const __attribute__((address_space(1))) unsigned int*)sl,
          (__attribute__((address_space(3))) unsigned int*)&ldsB[buf][1][dst], 16, 0, 0);
    }
  };

  float run_d[2][4];
  int run_c[2][4];
#pragma unroll
  for (int m = 0; m < 2; ++m)
#pragma unroll
    for (int j = 0; j < 4; ++j) { run_d[m][j] = 1e30f; run_c[m][j] = 0; }

  f32x4 acc[2][4] = {};
  stageB(0, 0);
  for (int ct = 0; ct < NCT; ++ct) {
    __syncthreads();                  // vmcnt(0) drain -> tile ct ready
    if (ct < NCT - 1) stageB((ct + 1) & 1, ct + 1);
    int buf = ct & 1;
#pragma unroll
    for (int ks = 0; ks < 8; ++ks) {
#pragma unroll
      for (int n = 0; n < 4; ++n) {
        int X = (ks * 4 + h4) ^ (l15 & 7);
        const unsigned short* bp = &ldsB[buf][0][(n * 16 + l15) * DDIM + X * 8];
        s16x8 bh = *(const s16x8*)bp;
        s16x8 bl = *(const s16x8*)(bp + CT * DDIM);   // lo array is contiguous after hi
        acc[0][n] = __builtin_amdgcn_mfma_f32_16x16x32_bf16(ah[0][ks], bh, acc[0][n], 0, 0, 0);
        acc[1][n] = __builtin_amdgcn_mfma_f32_16x16x32_bf16(ah[1][ks], bh, acc[1][n], 0, 0, 0);
        acc[0][n] = __builtin_amdgcn_mfma_f32_16x16x32_bf16(ah[0][ks], bl, acc[0][n], 0, 0, 0);
        acc[1][n] = __builtin_amdgcn_mfma_f32_16x16x32_bf16(ah[1][ks], bl, acc[1][n], 0, 0, 0);
        acc[0][n] = __builtin_amdgcn_mfma_f32_16x16x32_bf16(al[0][ks], bh, acc[0][n], 0, 0, 0);
        acc[1][n] = __builtin_amdgcn_mfma_f32_16x16x32_bf16(al[1][ks], bh, acc[1][n], 0, 0, 0);
      }
    }
    // fold this ct-tile into the running argmin (n ascending: first-index ties)
#pragma unroll
    for (int n = 0; n < 4; ++n) {
      int c = ct * CT + n * 16 + l15;
      float es = ensq[c];
#pragma unroll
      for (int m = 0; m < 2; ++m)
#pragma unroll
        for (int j = 0; j < 4; ++j) {
          float d = fmaf(-2.f, acc[m][n][j], es);
          if (d < run_d[m][j]) { run_d[m][j] = d; run_c[m][j] = c; }
          acc[m][n][j] = 0.f;
        }
    }
  }

  // rows are wave-private: pure 16-lane shuffle reduce, direct idx write
#pragma unroll
  for (int m = 0; m < 2; ++m)
#pragma unroll
    for (int j = 0; j < 4; ++j) {
      float bd = run_d[m][j];
      int bc = run_c[m][j];
#pragma unroll
      for (int s = 1; s < 16; s <<= 1) {
        float od = __shfl_xor(bd, s, 64);
        int oc = __shfl_xor(bc, s, 64);
        if (od < bd || (od == bd && oc < bc)) { bd = od; bc = oc; }
      }
      if (l15 == 0) idx[wrow + m * 16 + h4 * 4 + j] = bc;
    }
}

// ---------------- fused outputs: quantized, loss, histogram, one-hot scatter ----------------
// (one-hot zeros come from a hipMemsetAsync fill before this kernel)
__global__ __launch_bounds__(256) void outputs_k(const float* __restrict__ f,
    const int* __restrict__ idx, const float* __restrict__ en,
    float* __restrict__ outq, float* __restrict__ enc,
    int* __restrict__ hist, double* __restrict__ lacc) {
  int wid = threadIdx.x >> 6, lane = threadIdx.x & 63;
  int n = blockIdx.x * 4 + wid;
  int id = idx[n];
  float4 fv = ((const float4*)(f + (size_t)n * DDIM))[lane];
  float ss = wred(fv.x * fv.x + fv.y * fv.y + fv.z * fv.z + fv.w * fv.w);
  float mx = fmaxf(sqrtf(ss), 1e-12f);
  float4 ev = ((const float4*)(en + (size_t)id * DDIM))[lane];
  ((float4*)(outq + (size_t)n * DDIM))[lane] = ev;   // quantized_st == en[idx]
  float dx = ev.x - fv.x / mx;
  float dy = ev.y - fv.y / mx;
  float dz = ev.z - fv.z / mx;
  float dw = ev.w - fv.w / mx;
  float ls = wred(dx * dx + dy * dy + dz * dz + dw * dw);
  if (lane == 0) {
    atomicAdd(&lacc[blockIdx.x & 255], (double)ls);
    atomicAdd(&hist[id], 1);
    enc[(size_t)n * KCODES + id] = 1.0f;             // scatter the single 1
  }
}

// ---------------- finalize scalars ----------------
__global__ __launch_bounds__(256) void finalize_k(const int* __restrict__ hist,
    const double* __restrict__ lacc, float* __restrict__ out) {
  __shared__ double sd[256];
  __shared__ double se[256];
  int t = threadIdx.x;
  double e = 0.0;
#pragma unroll
  for (int i = 0; i < 4; ++i) {
    int c = hist[t * 4 + i];
    float p = (float)c * (1.0f / 131072.0f);
    e += (double)(p * logf(p + 1e-10f));
  }
  sd[t] = lacc[t];
  se[t] = e;
  __syncthreads();
  for (int s = 128; s > 0; s >>= 1) {
    if (t < s) { sd[t] += sd[t + s]; se[t] += se[t + s]; }
    __syncthreads();
  }
  if (t == 0) {
    out[33554432] = (float)(1.25 * (sd[0] / ((double)NROWS * (double)DDIM)));
    out[33554433] = expf(-(float)se[0]);
  }
}

extern "C" void kernel_launch(void* const* d_in, const int* in_sizes, int n_in,
                              void* d_out, int out_size, void* d_ws, size_t ws_size,
                              hipStream_t stream) {
  const float* f = (const float*)d_in[0];
  const float* W = (const float*)d_in[1];
  float* out = (float*)d_out;
  char* ws = (char*)d_ws;

  // ws layout (~2.6 MB)
  int*    hist = (int*)ws;                                   // 4 KB (memset)
  double* lacc = (double*)(ws + 4096);                       // 2 KB (memset)
  float*  ensq = (float*)(ws + 8192);                        // 4 KB
  float*  en   = (float*)(ws + 12288);                       // 1 MB
  unsigned short* enh = (unsigned short*)(ws + 12288 + 1048576);           // 512 KB
  unsigned short* enl = (unsigned short*)(ws + 12288 + 1048576 + 524288);  // 512 KB
  int*    idx  = (int*)(ws + 12288 + 2097152);               // 512 KB

  // big scratch inside d_out's encodings region; gemm3 consumes it BEFORE the
  // enc-region memset + outputs_k overwrite it.
  char* ob = (char*)d_out;
  const size_t S = 134217984;   // 256-aligned, past quantized+scalars
  unsigned short* fnh = (unsigned short*)(ob + S);                 // 64 MB
  unsigned short* fnl = (unsigned short*)(ob + S + 67108864);      // 64 MB
  float* enc = out + 33554434;

  hipMemsetAsync(ws, 0, 8192, stream);
  prep_w<<<KCODES / 4, 256, 0, stream>>>(W, en, enh, enl, ensq);
  prep_f<<<NROWS / 4, 256, 0, stream>>>(f, fnh, fnl);
  gemm3<<<NROWS / BM2, 512, 0, stream>>>(fnh, fnl, enh, enl, ensq, idx);
  hipMemsetAsync((void*)enc, 0, 536870912ULL, stream);   // zero one-hot region
  outputs_k<<<NROWS / 4, 256, 0, stream>>>(f, idx, en, out, enc, hist, lacc);
  finalize_k<<<1, 256, 0, stream>>>(hist, lacc, out);
}